// Round 8
// baseline (206.835 us; speedup 1.0000x reference)
//
#include <hip/hip_runtime.h>
#include <cstdint>
#include <cstddef>

// ---------------------------------------------------------------------------
// MHA block: out = proj( causal_softmax( (xWq)(xWk)^T / 8 ) (xWv) )
// B=4, T=2048, C=1024, H=16, D=64.  All GEMM-shaped compute on bf16 MFMA.
// ---------------------------------------------------------------------------

typedef short bf16x8 __attribute__((ext_vector_type(8)));
typedef float f32x4 __attribute__((ext_vector_type(4)));

#define MFMA32(a, b, c) __builtin_amdgcn_mfma_f32_16x16x32_bf16((a), (b), (c), 0, 0, 0)

__device__ __forceinline__ unsigned short f2b(float f) {
  unsigned int x = __builtin_bit_cast(unsigned int, f);
  x += 0x7fffu + ((x >> 16) & 1u);
  return (unsigned short)(x >> 16);
}

__device__ __forceinline__ unsigned int pack2(float a, float b) {
  return (unsigned int)f2b(a) | ((unsigned int)f2b(b) << 16);
}

__device__ __forceinline__ unsigned int cvtpk(float a, float b) {
  unsigned int r;
  asm("v_cvt_pk_bf16_f32 %0, %1, %2" : "=v"(r) : "v"(a), "v"(b));
  return r;
}

__device__ __forceinline__ float exp2v(float x) {
  float r;
  asm("v_exp_f32 %0, %1" : "=v"(r) : "v"(x));
  return r;
}

__device__ __forceinline__ void gload16(const void* g, void* l) {
  __builtin_amdgcn_global_load_lds(
      (const __attribute__((address_space(1))) void*)g,
      (__attribute__((address_space(3))) void*)l, 16, 0, 0);
}

// ---------------------------------------------------------------------------
__global__ __launch_bounds__(256) void k_conv_x(const float* __restrict__ in,
                                                unsigned short* __restrict__ out, int n4) {
  int i = blockIdx.x * 256 + threadIdx.x;
  if (i >= n4) return;
  float4 v = reinterpret_cast<const float4*>(in)[i];
  ushort4 o;
  o.x = f2b(v.x); o.y = f2b(v.y); o.z = f2b(v.z); o.w = f2b(v.w);
  reinterpret_cast<ushort4*>(out)[i] = o;
}

// ---------------------------------------------------------------------------
__global__ __launch_bounds__(256) void k_transpose(const float* __restrict__ in,
                                                   unsigned short* __restrict__ out,
                                                   int R, int C) {
  __shared__ float tile[32][33];
  int c0 = blockIdx.x * 32, r0 = blockIdx.y * 32;
  int tx = threadIdx.x & 31, ty = threadIdx.x >> 5;
#pragma unroll
  for (int j = 0; j < 4; ++j)
    tile[ty + 8 * j][tx] = in[(size_t)(r0 + ty + 8 * j) * C + c0 + tx];
  __syncthreads();
#pragma unroll
  for (int j = 0; j < 4; ++j)
    out[(size_t)(c0 + ty + 8 * j) * R + r0 + tx] = f2b(tile[tx][ty + 8 * j]);
}

// ---------------------------------------------------------------------------
// bf16 GEMM (m97-style mainloop, unchanged from R7), 128x128 tile, BK=64.
// EPI=0: LDS-bounce epilogue -> q/k/v ws (q pre-scaled log2e/8; k,v swizzled;
//        v transposed).  EPI=1: direct f32 row-major out.
// ---------------------------------------------------------------------------
template <int EPI>
__global__ __launch_bounds__(256) void k_gemm(const unsigned short* __restrict__ A,
                                              const unsigned short* __restrict__ Bt,
                                              float* __restrict__ outF,
                                              unsigned short* __restrict__ q_ws,
                                              unsigned short* __restrict__ k_ws,
                                              unsigned short* __restrict__ v_ws,
                                              int M, int N) {
  constexpr int K = 1024;
  __shared__ unsigned short smem[16384];  // As | Bs; epilogue reuses
  unsigned short* As = smem;
  unsigned short* Bs = smem + 8192;
  const int bn = blockIdx.x, bm = blockIdx.y;
  const int tid = threadIdx.x;
  const int w = tid >> 6, lane = tid & 63;
  const int wm = w >> 1, wn = w & 1;
  const int c = lane & 15, g = lane >> 4;

  f32x4 acc[4][4];
#pragma unroll
  for (int i = 0; i < 4; ++i)
#pragma unroll
    for (int j = 0; j < 4; ++j) acc[i][j] = (f32x4){0.f, 0.f, 0.f, 0.f};

  const int srow = 32 * w + (lane >> 3);
  const int scol = 8 * (lane & 7);
  const unsigned short* Ag = A + (size_t)(bm * 128 + srow) * K + scol;
  const unsigned short* Bg = Bt + (size_t)(bn * 128 + srow) * K + scol;
  char* AsB = (char*)As + w * 4096;
  char* BsB = (char*)Bs + w * 4096;

  for (int kt = 0; kt < K / 64; ++kt) {
    const int kb = kt * 64;
    __syncthreads();
#pragma unroll
    for (int i = 0; i < 4; ++i) {
      gload16(Ag + (size_t)(8 * i) * K + kb, AsB + i * 1024);
      gload16(Bg + (size_t)(8 * i) * K + kb, BsB + i * 1024);
    }
    asm volatile("s_waitcnt vmcnt(0)" ::: "memory");
    __syncthreads();
#pragma unroll
    for (int u = 0; u < 2; ++u) {
      bf16x8 af[4], bfr[4];
#pragma unroll
      for (int mf = 0; mf < 4; ++mf)
        af[mf] = *(const bf16x8*)((const char*)As + (wm * 64 + mf * 16 + c) * 128 + u * 64 + g * 16);
#pragma unroll
      for (int nf = 0; nf < 4; ++nf)
        bfr[nf] = *(const bf16x8*)((const char*)Bs + (wn * 64 + nf * 16 + c) * 128 + u * 64 + g * 16);
#pragma unroll
      for (int mf = 0; mf < 4; ++mf)
#pragma unroll
        for (int nf = 0; nf < 4; ++nf)
          acc[mf][nf] = MFMA32(af[mf], bfr[nf], acc[mf][nf]);
    }
  }

  const int rowb = bm * 128 + wm * 64;
  const int colb = bn * 128 + wn * 64;
  if (EPI == 1) {
#pragma unroll
    for (int mf = 0; mf < 4; ++mf)
#pragma unroll
      for (int nf = 0; nf < 4; ++nf)
#pragma unroll
        for (int r = 0; r < 4; ++r) {
          int row = rowb + mf * 16 + 4 * g + r;
          int col = colb + nf * 16 + c;
          outF[(size_t)row * N + col] = acc[mf][nf][r];
        }
  } else {
    const int sec = colb >> 10;
    const int hh = (colb & 1023) >> 6;
    const int b = rowb >> 11, t0 = rowb & 2047;
    unsigned short* Lw = smem + w * 4096;

    __syncthreads();
    if (sec < 2) {
      const float sc = (sec == 0) ? 0.125f * 1.4426950408889634f : 1.f;
#pragma unroll
      for (int mf = 0; mf < 4; ++mf)
#pragma unroll
        for (int nf = 0; nf < 4; ++nf)
#pragma unroll
          for (int r = 0; r < 4; ++r)
            Lw[(16 * mf + 4 * g + r) * 64 + 16 * nf + c] = f2b(acc[mf][nf][r] * sc);
    } else {
#pragma unroll
      for (int mf = 0; mf < 4; ++mf)
#pragma unroll
        for (int nf = 0; nf < 4; ++nf)
#pragma unroll
          for (int rr = 0; rr < 2; ++rr)
            *(unsigned int*)&Lw[(16 * nf + c) * 64 + 16 * mf + 4 * g + 2 * rr] =
                pack2(acc[mf][nf][2 * rr], acc[mf][nf][2 * rr + 1]);
    }
    asm volatile("s_waitcnt lgkmcnt(0)" ::: "memory");
    const int rw = lane >> 3, ch = lane & 7;
    const int chx = ch ^ rw;
    if (sec == 0) {
      unsigned short* dst = q_ws + ((size_t)(b * 16 + hh) * 2048 + t0) * 64;
#pragma unroll
      for (int i = 0; i < 8; ++i) {
        int tl = i * 8 + rw;
        *(bf16x8*)(dst + (size_t)tl * 64 + ch * 8) = *(const bf16x8*)&Lw[tl * 64 + ch * 8];
      }
    } else if (sec == 1) {
      unsigned short* dst = k_ws + ((size_t)(b * 16 + hh) * 2048 + t0) * 64;
#pragma unroll
      for (int i = 0; i < 8; ++i) {
        int tl = i * 8 + rw;
        *(bf16x8*)(dst + (size_t)tl * 64 + chx * 8) = *(const bf16x8*)&Lw[tl * 64 + ch * 8];
      }
    } else {
      unsigned short* dst = v_ws + (size_t)(b * 16 + hh) * 64 * 2048 + t0;
#pragma unroll
      for (int i = 0; i < 8; ++i) {
        int dl = i * 8 + rw;
        *(bf16x8*)(dst + (size_t)dl * 2048 + chx * 8) = *(const bf16x8*)&Lw[dl * 64 + ch * 8];
      }
    }
  }
}

// ---------------------------------------------------------------------------
// Flash attention, causal. 256 blocks x 512 threads (8 waves), 1 block/CU.
// Wave owns 32 q-rows (two 16-row groups rg0/rg1) -> every K/V LDS fragment
// read feeds 2x MFMA (halves per-q-row LDS-read traffic; attn is LDS-bound).
// Block = 256 q-rows; paired mirror tiles (xi, 7-xi) -> uniform 36 kt.
// KVBLK=64 double-buffered, counted vmcnt(2), raw s_barrier; swapped QK^T;
// per-lane online softmax per rg; log2e folded into q; defer-max; cvt_pk.
// ---------------------------------------------------------------------------
__global__ __launch_bounds__(512) void k_attn(const unsigned short* __restrict__ q_ws,
                                              const unsigned short* __restrict__ k_ws,
                                              const unsigned short* __restrict__ v_ws,
                                              unsigned short* __restrict__ y_ws) {
  constexpr int T = 2048;
  __shared__ unsigned short Ks[2][64 * 64];
  __shared__ unsigned short Vs[2][64 * 64];
  // 256 blocks: XCD (id%8) gets 32 consecutive blocks = 8 contiguous bh planes
  const int f = blockIdx.x;
  const int f2 = (f & 7) * 32 + (f >> 3);
  const int bh = f2 >> 2;
  const int xi = f2 & 3;
  const int tid = threadIdx.x, w = tid >> 6, lane = tid & 63;
  const int c = lane & 15, g = lane >> 4;
  const int cl = c & 7;
  const size_t base = (size_t)bh * T * 64;
  const unsigned short* Kb = k_ws + base;
  const unsigned short* Vb = v_ws + base;
  const unsigned short* Qb = q_ws + base;

  const int srow = w * 8 + (lane >> 3);
  const int sch = lane & 7;

#pragma unroll 1
  for (int ph = 0; ph < 2; ++ph) {
    const int q0 = (ph == 0 ? xi : 7 - xi) * 256;
    const int qb = q0 + 32 * w;       // wave's first q-row
    const int qrow0 = qb + c;         // rg0 lane row
    const int qrow1 = qb + 16 + c;    // rg1 lane row
    const int n_kt = (q0 >> 6) + 4;
    bf16x8 qf0[2], qf1[2];
#pragma unroll
    for (int u = 0; u < 2; ++u) {
      qf0[u] = *(const bf16x8*)(Qb + (size_t)qrow0 * 64 + 32 * u + 8 * g);
      qf1[u] = *(const bf16x8*)(Qb + (size_t)qrow1 * 64 + 32 * u + 8 * g);
    }

    f32x4 yacc[2][4];
#pragma unroll
    for (int rg = 0; rg < 2; ++rg)
#pragma unroll
      for (int i = 0; i < 4; ++i) yacc[rg][i] = (f32x4){0.f, 0.f, 0.f, 0.f};
    float m0 = -1e30f, m1 = -1e30f, l0 = 0.f, l1 = 0.f;

    __syncthreads();  // prior phase fully done before restaging buf 0
    gload16(Kb + (size_t)srow * 64 + sch * 8, (char*)&Ks[0][0] + w * 1024);
    gload16(Vb + (size_t)srow * T + sch * 8, (char*)&Vs[0][0] + w * 1024);

#pragma unroll 1
    for (int kt = 0; kt < n_kt; ++kt) {
      const int k0 = kt * 64;
      const int cur = kt & 1;
      if (kt + 1 < n_kt) {
        const int k0n = k0 + 64;
        gload16(Kb + (size_t)(k0n + srow) * 64 + sch * 8, (char*)&Ks[cur ^ 1][0] + w * 1024);
        gload16(Vb + (size_t)srow * T + k0n + sch * 8, (char*)&Vs[cur ^ 1][0] + w * 1024);
        asm volatile("s_waitcnt vmcnt(2)" ::: "memory");
      } else {
        asm volatile("s_waitcnt vmcnt(0)" ::: "memory");
      }
      __builtin_amdgcn_s_barrier();

      if (k0 <= qb + 31) {  // wave-uniform
        const char* KsC = (const char*)&Ks[cur][0];
        const char* VsC = (const char*)&Vs[cur][0];
        // S^T for both row groups; K-fragments read ONCE
        f32x4 s0[4], s1[4];
        __builtin_amdgcn_s_setprio(1);
#pragma unroll
        for (int tf = 0; tf < 4; ++tf) {
          bf16x8 kf0 = *(const bf16x8*)(KsC + (16 * tf + c) * 128 + (g ^ cl) * 16);
          bf16x8 kf1 = *(const bf16x8*)(KsC + (16 * tf + c) * 128 + ((4 + g) ^ cl) * 16);
          f32x4 z = (f32x4){0.f, 0.f, 0.f, 0.f};
          z = MFMA32(kf0, qf0[0], z);
          s0[tf] = MFMA32(kf1, qf0[1], z);
          f32x4 z2 = (f32x4){0.f, 0.f, 0.f, 0.f};
          z2 = MFMA32(kf0, qf1[0], z2);
          s1[tf] = MFMA32(kf1, qf1[1], z2);
        }
        __builtin_amdgcn_s_setprio(0);
        if (k0 + 63 > qb) {  // causal mask rg0
#pragma unroll
          for (int tf = 0; tf < 4; ++tf)
#pragma unroll
            for (int r = 0; r < 4; ++r)
              if (k0 + 16 * tf + 4 * g + r > qrow0) s0[tf][r] = -1e30f;
        }
        if (k0 + 63 > qb + 16) {  // causal mask rg1
#pragma unroll
          for (int tf = 0; tf < 4; ++tf)
#pragma unroll
            for (int r = 0; r < 4; ++r)
              if (k0 + 16 * tf + 4 * g + r > qrow1) s1[tf][r] = -1e30f;
        }
        // per-rg tile max + cross-g reduce
        float mxa = -1e30f, mxb = -1e30f;
#pragma unroll
        for (int tf = 0; tf < 4; ++tf) {
          mxa = fmaxf(mxa, fmaxf(fmaxf(s0[tf][0], s0[tf][1]), fmaxf(s0[tf][2], s0[tf][3])));
          mxb = fmaxf(mxb, fmaxf(fmaxf(s1[tf][0], s1[tf][1]), fmaxf(s1[tf][2], s1[tf][3])));
        }
        mxa = fmaxf(mxa, __shfl_xor(mxa, 16));
        mxa = fmaxf(mxa, __shfl_xor(mxa, 32));
        mxb = fmaxf(mxb, __shfl_xor(mxb, 16));
        mxb = fmaxf(mxb, __shfl_xor(mxb, 32));
        // joint defer-max (log2 units)
        if (__any(fmaxf(mxa - m0, mxb - m1) > 11.5f)) {
          float mn0 = fmaxf(m0, mxa), mn1 = fmaxf(m1, mxb);
          float c0 = exp2v(m0 - mn0), c1 = exp2v(m1 - mn1);
          l0 *= c0; l1 *= c1;
#pragma unroll
          for (int i = 0; i < 4; ++i) { yacc[0][i] *= c0; yacc[1][i] *= c1; }
          m0 = mn0; m1 = mn1;
        }
        float p0[16], p1[16];
#pragma unroll
        for (int tf = 0; tf < 4; ++tf)
#pragma unroll
          for (int r = 0; r < 4; ++r) {
            p0[tf * 4 + r] = exp2v(s0[tf][r] - m0);
            p1[tf * 4 + r] = exp2v(s1[tf][r] - m1);
          }
        float psa = ((p0[0] + p0[1]) + (p0[2] + p0[3])) + ((p0[4] + p0[5]) + (p0[6] + p0[7]));
        psa += ((p0[8] + p0[9]) + (p0[10] + p0[11])) + ((p0[12] + p0[13]) + (p0[14] + p0[15]));
        float psb = ((p1[0] + p1[1]) + (p1[2] + p1[3])) + ((p1[4] + p1[5]) + (p1[6] + p1[7]));
        psb += ((p1[8] + p1[9]) + (p1[10] + p1[11])) + ((p1[12] + p1[13]) + (p1[14] + p1[15]));
        l0 += psa; l1 += psb;

        // PV per 32-k half; V-fragments read ONCE, feed both rgs
        const int a2 = 2 * (g & 1);
        const int srcA = 16 * a2 + c, srcB = srcA + 16;
        const bool f1 = (g >= 2);
#pragma unroll
        for (int h = 0; h < 2; ++h) {
          union { unsigned int u[4]; bf16x8 v; } pfa, pfb;
          {
            unsigned int lo0 = cvtpk(p0[8 * h + 0], p0[8 * h + 1]);
            unsigned int hi0 = cvtpk(p0[8 * h + 2], p0[8 * h + 3]);
            unsigned int lo1 = cvtpk(p0[8 * h + 4], p0[8 * h + 5]);
            unsigned int hi1 = cvtpk(p0[8 * h + 6], p0[8 * h + 7]);
            unsigned int Al0 = __shfl(lo0, srcA), Ah0 = __shfl(hi0, srcA);
            unsigned int Al1 = __shfl(lo1, srcA), Ah1 = __shfl(hi1, srcA);
            unsigned int Bl0 = __shfl(lo0, srcB), Bh0 = __shfl(hi0, srcB);
            unsigned int Bl1 = __shfl(lo1, srcB), Bh1 = __shfl(hi1, srcB);
            pfa.u[0] = f1 ? Al1 : Al0;
            pfa.u[1] = f1 ? Ah1 : Ah0;
            pfa.u[2] = f1 ? Bl1 : Bl0;
            pfa.u[3] = f1 ? Bh1 : Bh0;
          }
          {
            unsigned int lo0 = cvtpk(p1[8 * h + 0], p1[8 * h + 1]);
            unsigned int hi0 = cvtpk(p1[8 * h + 2], p1[8 * h + 3]);
            unsigned int lo1 = cvtpk(p1[8 * h + 4], p1[8 * h + 5]);
            unsigned int hi1 = cvtpk(p1[8 * h + 6], p1[8 * h + 7]);
            unsigned int Al0 = __shfl(lo0, srcA), Ah0 = __shfl(hi0, srcA);
            unsigned int Al1 = __shfl(lo1, srcA), Ah1 = __shfl(hi1, srcA);
            unsigned int Bl0 = __shfl(lo0, srcB), Bh0 = __shfl(hi0, srcB);
            unsigned int Bl1 = __shfl(lo1, srcB), Bh1 = __shfl(hi1, srcB);
            pfb.u[0] = f1 ? Al1 : Al0;
            pfb.u[1] = f1 ? Ah1 : Ah0;
            pfb.u[2] = f1 ? Bl1 : Bl0;
            pfb.u[3] = f1 ? Bh1 : Bh0;
          }
          __builtin_amdgcn_s_setprio(1);
#pragma unroll
          for (int df = 0; df < 4; ++df) {
            bf16x8 vf = *(const bf16x8*)(VsC + (16 * df + c) * 128 + ((h * 4 + g) ^ cl) * 16);
            yacc[0][df] = MFMA32(vf, pfa.v, yacc[0][df]);
            yacc[1][df] = MFMA32(vf, pfb.v, yacc[1][df]);
          }
          __builtin_amdgcn_s_setprio(0);
        }
      }
      __builtin_amdgcn_s_barrier();
    }

    const int b = bh >> 4, hh = bh & 15;
    float lta = l0, ltb = l1;
    lta += __shfl_xor(lta, 16);
    lta += __shfl_xor(lta, 32);
    ltb += __shfl_xor(ltb, 16);
    ltb += __shfl_xor(ltb, 32);
    float inva = 1.f / lta, invb = 1.f / ltb;
#pragma unroll
    for (int df = 0; df < 4; ++df) {
      uint2 oa, ob;
      oa.x = cvtpk(yacc[0][df][0] * inva, yacc[0][df][1] * inva);
      oa.y = cvtpk(yacc[0][df][2] * inva, yacc[0][df][3] * inva);
      ob.x = cvtpk(yacc[1][df][0] * invb, yacc[1][df][1] * invb);
      ob.y = cvtpk(yacc[1][df][2] * invb, yacc[1][df][3] * invb);
      *(uint2*)(y_ws + (size_t)(b * 2048 + qrow0) * 1024 + hh * 64 + 16 * df + 4 * g) = oa;
      *(uint2*)(y_ws + (size_t)(b * 2048 + qrow1) * 1024 + hh * 64 + 16 * df + 4 * g) = ob;
    }
  }
}

// ---------------------------------------------------------------------------
extern "C" void kernel_launch(void* const* d_in, const int* in_sizes, int n_in,
                              void* d_out, int out_size, void* d_ws, size_t ws_size,
                              hipStream_t stream) {
  const float* x = (const float*)d_in[0];      // (4, 2048, 1024)
  const float* Wqkv = (const float*)d_in[1];   // (1024, 3072)
  const float* Wproj = (const float*)d_in[2];  // (1024, 1024)
  float* out = (float*)d_out;                  // (4, 2048, 1024)
  char* ws = (char*)d_ws;

  unsigned short* x_bf = (unsigned short*)(ws);                    // 16 MiB
  unsigned short* wqkvT = (unsigned short*)(ws + 16777216);        // 6 MiB
  unsigned short* wprojT = (unsigned short*)(ws + 23068672);       // 2 MiB
  unsigned short* q_ws = (unsigned short*)(ws + 25165824);         // 16 MiB
  unsigned short* k_ws = (unsigned short*)(ws + 41943040);         // 16 MiB
  unsigned short* v_ws = (unsigned short*)(ws + 58720256);         // 16 MiB
  unsigned short* y_ws = (unsigned short*)(ws + 75497472);         // 16 MiB

  k_conv_x<<<8192, 256, 0, stream>>>(x, x_bf, 2097152);
  k_transpose<<<dim3(96, 32), 256, 0, stream>>>(Wqkv, wqkvT, 1024, 3072);
  k_transpose<<<dim3(32, 32), 256, 0, stream>>>(Wproj, wprojT, 1024, 1024);
  k_gemm<0><<<dim3(24, 64), 256, 0, stream>>>(x_bf, wqkvT, nullptr, q_ws, k_ws, v_ws, 8192, 3072);
  k_attn<<<256, 512, 0, stream>>>(q_ws, k_ws, v_ws, y_ws);
  k_gemm<1><<<dim3(8, 64), 256, 0, stream>>>(y_ws, wprojT, out, nullptr, nullptr, nullptr, 8192, 1024);
}

// Round 9
// 186.438 us; speedup vs baseline: 1.1094x; 1.1094x over previous
//
#include <hip/hip_runtime.h>
#include <cstdint>
#include <cstddef>

// ---------------------------------------------------------------------------
// MHA block: out = proj( causal_softmax( (xWq)(xWk)^T / 8 ) (xWv) )
// B=4, T=2048, C=1024, H=16, D=64.  All GEMM-shaped compute on bf16 MFMA.
// ---------------------------------------------------------------------------

typedef short bf16x8 __attribute__((ext_vector_type(8)));
typedef float f32x4 __attribute__((ext_vector_type(4)));

#define MFMA32(a, b, c) __builtin_amdgcn_mfma_f32_16x16x32_bf16((a), (b), (c), 0, 0, 0)

__device__ __forceinline__ unsigned short f2b(float f) {
  unsigned int x = __builtin_bit_cast(unsigned int, f);
  x += 0x7fffu + ((x >> 16) & 1u);
  return (unsigned short)(x >> 16);
}

__device__ __forceinline__ unsigned int pack2(float a, float b) {
  return (unsigned int)f2b(a) | ((unsigned int)f2b(b) << 16);
}

__device__ __forceinline__ unsigned int cvtpk(float a, float b) {
  unsigned int r;
  asm("v_cvt_pk_bf16_f32 %0, %1, %2" : "=v"(r) : "v"(a), "v"(b));
  return r;
}

__device__ __forceinline__ float exp2v(float x) {
  float r;
  asm("v_exp_f32 %0, %1" : "=v"(r) : "v"(x));
  return r;
}

__device__ __forceinline__ void gload16(const void* g, void* l) {
  __builtin_amdgcn_global_load_lds(
      (const __attribute__((address_space(1))) void*)g,
      (__attribute__((address_space(3))) void*)l, 16, 0, 0);
}

// ---------------------------------------------------------------------------
__global__ __launch_bounds__(256) void k_conv_x(const float* __restrict__ in,
                                                unsigned short* __restrict__ out, int n4) {
  int i = blockIdx.x * 256 + threadIdx.x;
  if (i >= n4) return;
  float4 v = reinterpret_cast<const float4*>(in)[i];
  ushort4 o;
  o.x = f2b(v.x); o.y = f2b(v.y); o.z = f2b(v.z); o.w = f2b(v.w);
  reinterpret_cast<ushort4*>(out)[i] = o;
}

// ---------------------------------------------------------------------------
__global__ __launch_bounds__(256) void k_transpose(const float* __restrict__ in,
                                                   unsigned short* __restrict__ out,
                                                   int R, int C) {
  __shared__ float tile[32][33];
  int c0 = blockIdx.x * 32, r0 = blockIdx.y * 32;
  int tx = threadIdx.x & 31, ty = threadIdx.x >> 5;
#pragma unroll
  for (int j = 0; j < 4; ++j)
    tile[ty + 8 * j][tx] = in[(size_t)(r0 + ty + 8 * j) * C + c0 + tx];
  __syncthreads();
#pragma unroll
  for (int j = 0; j < 4; ++j)
    out[(size_t)(c0 + ty + 8 * j) * R + r0 + tx] = f2b(tile[tx][ty + 8 * j]);
}

// ---------------------------------------------------------------------------
// bf16 GEMM (m97-style mainloop), 128x128 tile, BK=64, 4 waves, 64x64/wave.
// NEW (R9): LDS XOR-swizzle on As/Bs — staging source column pre-swizzled
//   (chunk_src = (lane&7)^(lane>>3), matching row&7), mainloop ds_read uses
//   chunk' = (u*4+g)^(c&7).  Same data reaches MFMA; conflicts -> ~0.
// EPI=0: LDS-bounce epilogue -> q/k/v ws (q pre-scaled log2e/8; k,v swizzled;
//        v transposed).  EPI=1: direct f32 row-major out.
// ---------------------------------------------------------------------------
template <int EPI>
__global__ __launch_bounds__(256) void k_gemm(const unsigned short* __restrict__ A,
                                              const unsigned short* __restrict__ Bt,
                                              float* __restrict__ outF,
                                              unsigned short* __restrict__ q_ws,
                                              unsigned short* __restrict__ k_ws,
                                              unsigned short* __restrict__ v_ws,
                                              int M, int N) {
  constexpr int K = 1024;
  __shared__ unsigned short smem[16384];  // As | Bs; epilogue reuses
  unsigned short* As = smem;
  unsigned short* Bs = smem + 8192;
  const int bn = blockIdx.x, bm = blockIdx.y;
  const int tid = threadIdx.x;
  const int w = tid >> 6, lane = tid & 63;
  const int wm = w >> 1, wn = w & 1;
  const int c = lane & 15, g = lane >> 4;
  const int cl8 = c & 7;

  f32x4 acc[4][4];
#pragma unroll
  for (int i = 0; i < 4; ++i)
#pragma unroll
    for (int j = 0; j < 4; ++j) acc[i][j] = (f32x4){0.f, 0.f, 0.f, 0.f};

  const int srow = 32 * w + (lane >> 3);
  // source chunk pre-swizzled so LDS chunk j of row r holds source chunk j^(r&7)
  const int scol = 8 * ((lane & 7) ^ (lane >> 3));
  const unsigned short* Ag = A + (size_t)(bm * 128 + srow) * K + scol;
  const unsigned short* Bg = Bt + (size_t)(bn * 128 + srow) * K + scol;
  char* AsB = (char*)As + w * 4096;
  char* BsB = (char*)Bs + w * 4096;

  for (int kt = 0; kt < K / 64; ++kt) {
    const int kb = kt * 64;
    __syncthreads();
#pragma unroll
    for (int i = 0; i < 4; ++i) {
      gload16(Ag + (size_t)(8 * i) * K + kb, AsB + i * 1024);
      gload16(Bg + (size_t)(8 * i) * K + kb, BsB + i * 1024);
    }
    asm volatile("s_waitcnt vmcnt(0)" ::: "memory");
    __syncthreads();
#pragma unroll
    for (int u = 0; u < 2; ++u) {
      bf16x8 af[4], bfr[4];
#pragma unroll
      for (int mf = 0; mf < 4; ++mf)
        af[mf] = *(const bf16x8*)((const char*)As + (wm * 64 + mf * 16 + c) * 128 +
                                  (((u * 4 + g) ^ cl8) * 16));
#pragma unroll
      for (int nf = 0; nf < 4; ++nf)
        bfr[nf] = *(const bf16x8*)((const char*)Bs + (wn * 64 + nf * 16 + c) * 128 +
                                   (((u * 4 + g) ^ cl8) * 16));
#pragma unroll
      for (int mf = 0; mf < 4; ++mf)
#pragma unroll
        for (int nf = 0; nf < 4; ++nf)
          acc[mf][nf] = MFMA32(af[mf], bfr[nf], acc[mf][nf]);
    }
  }

  const int rowb = bm * 128 + wm * 64;
  const int colb = bn * 128 + wn * 64;
  if (EPI == 1) {
#pragma unroll
    for (int mf = 0; mf < 4; ++mf)
#pragma unroll
      for (int nf = 0; nf < 4; ++nf)
#pragma unroll
        for (int r = 0; r < 4; ++r) {
          int row = rowb + mf * 16 + 4 * g + r;
          int col = colb + nf * 16 + c;
          outF[(size_t)row * N + col] = acc[mf][nf][r];
        }
  } else {
    const int sec = colb >> 10;
    const int hh = (colb & 1023) >> 6;
    const int b = rowb >> 11, t0 = rowb & 2047;
    unsigned short* Lw = smem + w * 4096;

    __syncthreads();
    if (sec < 2) {
      const float sc = (sec == 0) ? 0.125f * 1.4426950408889634f : 1.f;
#pragma unroll
      for (int mf = 0; mf < 4; ++mf)
#pragma unroll
        for (int nf = 0; nf < 4; ++nf)
#pragma unroll
          for (int r = 0; r < 4; ++r)
            Lw[(16 * mf + 4 * g + r) * 64 + 16 * nf + c] = f2b(acc[mf][nf][r] * sc);
    } else {
#pragma unroll
      for (int mf = 0; mf < 4; ++mf)
#pragma unroll
        for (int nf = 0; nf < 4; ++nf)
#pragma unroll
          for (int rr = 0; rr < 2; ++rr)
            *(unsigned int*)&Lw[(16 * nf + c) * 64 + 16 * mf + 4 * g + 2 * rr] =
                pack2(acc[mf][nf][2 * rr], acc[mf][nf][2 * rr + 1]);
    }
    asm volatile("s_waitcnt lgkmcnt(0)" ::: "memory");
    const int rw = lane >> 3, ch = lane & 7;
    const int chx = ch ^ rw;
    if (sec == 0) {
      unsigned short* dst = q_ws + ((size_t)(b * 16 + hh) * 2048 + t0) * 64;
#pragma unroll
      for (int i = 0; i < 8; ++i) {
        int tl = i * 8 + rw;
        *(bf16x8*)(dst + (size_t)tl * 64 + ch * 8) = *(const bf16x8*)&Lw[tl * 64 + ch * 8];
      }
    } else if (sec == 1) {
      unsigned short* dst = k_ws + ((size_t)(b * 16 + hh) * 2048 + t0) * 64;
#pragma unroll
      for (int i = 0; i < 8; ++i) {
        int tl = i * 8 + rw;
        *(bf16x8*)(dst + (size_t)tl * 64 + chx * 8) = *(const bf16x8*)&Lw[tl * 64 + ch * 8];
      }
    } else {
      unsigned short* dst = v_ws + (size_t)(b * 16 + hh) * 64 * 2048 + t0;
#pragma unroll
      for (int i = 0; i < 8; ++i) {
        int dl = i * 8 + rw;
        *(bf16x8*)(dst + (size_t)dl * 2048 + chx * 8) = *(const bf16x8*)&Lw[dl * 64 + ch * 8];
      }
    }
  }
}

// ---------------------------------------------------------------------------
// Flash attention, causal. 512 blocks x 512 threads (8 waves).  (R7 version:
// best measured ~83us; 16 q-rows/wave, 2 blocks/CU, double-buffered K/V,
// counted vmcnt(2) + raw s_barrier, swapped QK^T, defer-max, cvt_pk.)
// ---------------------------------------------------------------------------
__global__ __launch_bounds__(512) void k_attn(const unsigned short* __restrict__ q_ws,
                                              const unsigned short* __restrict__ k_ws,
                                              const unsigned short* __restrict__ v_ws,
                                              unsigned short* __restrict__ y_ws) {
  constexpr int T = 2048;
  __shared__ unsigned short Ks[2][64 * 64];
  __shared__ unsigned short Vs[2][64 * 64];
  const int f = blockIdx.x;
  const int f2 = (f & 7) * 64 + (f >> 3);
  const int bh = f2 >> 3;
  const int xi = f2 & 7;
  const int tid = threadIdx.x, w = tid >> 6, lane = tid & 63;
  const int c = lane & 15, g = lane >> 4;
  const int cl = c & 7;
  const size_t base = (size_t)bh * T * 64;
  const unsigned short* Kb = k_ws + base;
  const unsigned short* Vb = v_ws + base;
  const unsigned short* Qb = q_ws + base;

  const int srow = w * 8 + (lane >> 3);
  const int sch = lane & 7;

#pragma unroll 1
  for (int ph = 0; ph < 2; ++ph) {
    const int q0 = (ph == 0 ? xi : 15 - xi) * 128;
    const int qrow = q0 + 16 * w + c;
    const int q_max_wave = q0 + 16 * w + 15;
    const int n_kt = (q0 >> 6) + 2;
    bf16x8 qf[2];
#pragma unroll
    for (int u = 0; u < 2; ++u)
      qf[u] = *(const bf16x8*)(Qb + (size_t)qrow * 64 + 32 * u + 8 * g);

    f32x4 yacc[4];
#pragma unroll
    for (int i = 0; i < 4; ++i) yacc[i] = (f32x4){0.f, 0.f, 0.f, 0.f};
    float m_run = -1e30f, l_part = 0.f;

    __syncthreads();  // prior phase fully done before restaging buf 0
    gload16(Kb + (size_t)srow * 64 + sch * 8, (char*)&Ks[0][0] + w * 1024);
    gload16(Vb + (size_t)srow * T + sch * 8, (char*)&Vs[0][0] + w * 1024);

#pragma unroll 1
    for (int kt = 0; kt < n_kt; ++kt) {
      const int k0 = kt * 64;
      const int cur = kt & 1;
      if (kt + 1 < n_kt) {
        const int k0n = k0 + 64;
        gload16(Kb + (size_t)(k0n + srow) * 64 + sch * 8, (char*)&Ks[cur ^ 1][0] + w * 1024);
        gload16(Vb + (size_t)srow * T + k0n + sch * 8, (char*)&Vs[cur ^ 1][0] + w * 1024);
        asm volatile("s_waitcnt vmcnt(2)" ::: "memory");
      } else {
        asm volatile("s_waitcnt vmcnt(0)" ::: "memory");
      }
      __builtin_amdgcn_s_barrier();

      if (k0 <= q_max_wave) {
        const char* KsC = (const char*)&Ks[cur][0];
        const char* VsC = (const char*)&Vs[cur][0];
        f32x4 s[4];
        __builtin_amdgcn_s_setprio(1);
#pragma unroll
        for (int tf = 0; tf < 4; ++tf) {
          bf16x8 kf0 = *(const bf16x8*)(KsC + (16 * tf + c) * 128 + (g ^ cl) * 16);
          bf16x8 kf1 = *(const bf16x8*)(KsC + (16 * tf + c) * 128 + ((4 + g) ^ cl) * 16);
          f32x4 z = (f32x4){0.f, 0.f, 0.f, 0.f};
          z = MFMA32(kf0, qf[0], z);
          s[tf] = MFMA32(kf1, qf[1], z);
        }
        __builtin_amdgcn_s_setprio(0);
        if (k0 + 63 > q0 + 16 * w) {
#pragma unroll
          for (int tf = 0; tf < 4; ++tf)
#pragma unroll
            for (int r = 0; r < 4; ++r)
              if (k0 + 16 * tf + 4 * g + r > qrow) s[tf][r] = -1e30f;
        }
        float mx0 = fmaxf(fmaxf(s[0][0], s[0][1]), fmaxf(s[0][2], s[0][3]));
        float mx1 = fmaxf(fmaxf(s[1][0], s[1][1]), fmaxf(s[1][2], s[1][3]));
        float mx2 = fmaxf(fmaxf(s[2][0], s[2][1]), fmaxf(s[2][2], s[2][3]));
        float mx3 = fmaxf(fmaxf(s[3][0], s[3][1]), fmaxf(s[3][2], s[3][3]));
        float mx = fmaxf(fmaxf(mx0, mx1), fmaxf(mx2, mx3));
        mx = fmaxf(mx, __shfl_xor(mx, 16));
        mx = fmaxf(mx, __shfl_xor(mx, 32));
        if (__any(mx > m_run + 11.5f)) {
          float m_new = fmaxf(m_run, mx);
          float corr = exp2v(m_run - m_new);
          l_part *= corr;
#pragma unroll
          for (int i = 0; i < 4; ++i) yacc[i] *= corr;
          m_run = m_new;
        }
        float p[16];
#pragma unroll
        for (int tf = 0; tf < 4; ++tf)
#pragma unroll
          for (int r = 0; r < 4; ++r) p[tf * 4 + r] = exp2v(s[tf][r] - m_run);
        float ps = ((p[0] + p[1]) + (p[2] + p[3])) + ((p[4] + p[5]) + (p[6] + p[7]));
        ps += ((p[8] + p[9]) + (p[10] + p[11])) + ((p[12] + p[13]) + (p[14] + p[15]));
        l_part += ps;

#pragma unroll
        for (int h = 0; h < 2; ++h) {
          unsigned int lo0 = cvtpk(p[8 * h + 0], p[8 * h + 1]);
          unsigned int hi0 = cvtpk(p[8 * h + 2], p[8 * h + 3]);
          unsigned int lo1 = cvtpk(p[8 * h + 4], p[8 * h + 5]);
          unsigned int hi1 = cvtpk(p[8 * h + 6], p[8 * h + 7]);
          int a2 = 2 * (g & 1);
          int srcA = 16 * a2 + c, srcB = srcA + 16;
          unsigned int Al0 = __shfl(lo0, srcA), Ah0 = __shfl(hi0, srcA);
          unsigned int Al1 = __shfl(lo1, srcA), Ah1 = __shfl(hi1, srcA);
          unsigned int Bl0 = __shfl(lo0, srcB), Bh0 = __shfl(hi0, srcB);
          unsigned int Bl1 = __shfl(lo1, srcB), Bh1 = __shfl(hi1, srcB);
          bool f1 = (g >= 2);
          union { unsigned int u[4]; bf16x8 v; } pf;
          pf.u[0] = f1 ? Al1 : Al0;
          pf.u[1] = f1 ? Ah1 : Ah0;
          pf.u[2] = f1 ? Bl1 : Bl0;
          pf.u[3] = f1 ? Bh1 : Bh0;
          __builtin_amdgcn_s_setprio(1);
#pragma unroll
          for (int df = 0; df < 4; ++df) {
            bf16x8 vf = *(const bf16x8*)(VsC + (16 * df + c) * 128 + ((h * 4 + g) ^ cl) * 16);
            yacc[df] = MFMA32(vf, pf.v, yacc[df]);
          }
          __builtin_amdgcn_s_setprio(0);
        }
      }
      __builtin_amdgcn_s_barrier();
    }

    float lt = l_part;
    lt += __shfl_xor(lt, 16);
    lt += __shfl_xor(lt, 32);
    float inv = 1.f / lt;
    const int b = bh >> 4, hh = bh & 15;
#pragma unroll
    for (int df = 0; df < 4; ++df) {
      uint2 o;
      o.x = cvtpk(yacc[df][0] * inv, yacc[df][1] * inv);
      o.y = cvtpk(yacc[df][2] * inv, yacc[df][3] * inv);
      *(uint2*)(y_ws + (size_t)(b * 2048 + qrow) * 1024 + hh * 64 + 16 * df + 4 * g) = o;
    }
  }
}

// ---------------------------------------------------------------------------
extern "C" void kernel_launch(void* const* d_in, const int* in_sizes, int n_in,
                              void* d_out, int out_size, void* d_ws, size_t ws_size,
                              hipStream_t stream) {
  const float* x = (const float*)d_in[0];      // (4, 2048, 1024)
  const float* Wqkv = (const float*)d_in[1];   // (1024, 3072)
  const float* Wproj = (const float*)d_in[2];  // (1024, 1024)
  float* out = (float*)d_out;                  // (4, 2048, 1024)
  char* ws = (char*)d_ws;

  unsigned short* x_bf = (unsigned short*)(ws);                    // 16 MiB
  unsigned short* wqkvT = (unsigned short*)(ws + 16777216);        // 6 MiB
  unsigned short* wprojT = (unsigned short*)(ws + 23068672);       // 2 MiB
  unsigned short* q_ws = (unsigned short*)(ws + 25165824);         // 16 MiB
  unsigned short* k_ws = (unsigned short*)(ws + 41943040);         // 16 MiB
  unsigned short* v_ws = (unsigned short*)(ws + 58720256);         // 16 MiB
  unsigned short* y_ws = (unsigned short*)(ws + 75497472);         // 16 MiB

  k_conv_x<<<8192, 256, 0, stream>>>(x, x_bf, 2097152);
  k_transpose<<<dim3(96, 32), 256, 0, stream>>>(Wqkv, wqkvT, 1024, 3072);
  k_transpose<<<dim3(32, 32), 256, 0, stream>>>(Wproj, wprojT, 1024, 1024);
  k_gemm<0><<<dim3(24, 64), 256, 0, stream>>>(x_bf, wqkvT, nullptr, q_ws, k_ws, v_ws, 8192, 3072);
  k_attn<<<512, 512, 0, stream>>>(q_ws, k_ws, v_ws, y_ws);
  k_gemm<1><<<dim3(8, 64), 256, 0, stream>>>(y_ws, wprojT, out, nullptr, nullptr, nullptr, 8192, 1024);
}